// Round 7
// baseline (208.257 us; speedup 1.0000x reference)
//
#include <hip/hip_runtime.h>
#include <hip/hip_bf16.h>

constexpr int kN = 8192;
constexpr int kD = 128;
constexpr int BMB = 32;     // rows per block in main kernel (2 row-groups x 16)
constexpr int BK = 64;      // j-window per iteration (2 col-halves x 32)
constexpr int JSPLIT = 4;   // j-range strips (grid.y)
constexpr int LDB = 72;     // padded LDS row stride (bf16 elems) -> 144B

typedef __bf16 v8bf __attribute__((ext_vector_type(8)));
typedef float  v4f  __attribute__((ext_vector_type(4)));

// Exact same K_raw formula as reference (pre-normalization, pre-diagonal).
// EXACT round-2/4/6-proven body.
__device__ __forceinline__ float kraw_f(float4 ci, float sqi, float4 cj, float sqj) {
    float d2 = sqi + sqj - 2.0f * (ci.x * cj.x + ci.y * cj.y + ci.z * cj.z);
    d2 = fmaxf(d2, 1e-12f);
    float Dd = __builtin_amdgcn_sqrtf(d2) + 1e-6f;          // D = sqrt(max(d2,1e-12)) + 1e-6
    float a = 0.5f * (ci.w + cj.w);
    float p = __builtin_amdgcn_exp2f(-a * __builtin_amdgcn_logf(Dd));  // D^-a
    p = fminf(fmaxf(p, 1e-8f), 1000.0f);
    float K = p * __builtin_amdgcn_exp2f(Dd * -0.12022458674074695f);  // *exp(-D/12)
    return fminf(K, 1000.0f);  // K >= 0 always
}

// --- kernel 1: pack coords+alpha into float4 (proven) ----------------------
__global__ void pack_k(const float* __restrict__ coords, const float* __restrict__ alpha,
                       float4* __restrict__ c4) {
    int j = blockIdx.x * 256 + threadIdx.x;
    if (j < kN) {
        c4[j] = make_float4(coords[3 * j], coords[3 * j + 1], coords[3 * j + 2], alpha[j]);
    }
}

// --- kernel 2: transpose latent [N][128] f32 -> latT [128][N] bf16 (proven) -
__global__ void transpose_k(const float* __restrict__ latent, __bf16* __restrict__ latT) {
    __shared__ float tile[32][33];
    int t = threadIdx.x;
    int tx = t & 31, ty = t >> 5;          // 32 x 8
    int j0 = blockIdx.x * 32, d0 = blockIdx.y * 32;
    #pragma unroll
    for (int i = 0; i < 32; i += 8)
        tile[ty + i][tx] = latent[(size_t)(j0 + ty + i) * kD + d0 + tx];
    __syncthreads();
    #pragma unroll
    for (int i = 0; i < 32; i += 8)
        latT[(size_t)(d0 + ty + i) * kN + j0 + tx] = (__bf16)tile[tx][ty + i];
}

// --- kernel 3: row partial sums -> atomicAdd into rsum (round-6 proven) ----
__global__ __launch_bounds__(256) void rowsum_k(const float4* __restrict__ c4,
                                                float* __restrict__ rsum) {
    int w = threadIdx.x >> 6, lane = threadIdx.x & 63;
    int i = blockIdx.x * 4 + w;
    int jbase = blockIdx.y * (kN / JSPLIT);
    float4 ci = c4[i];
    float sqi = ci.x * ci.x + ci.y * ci.y + ci.z * ci.z;
    float s = 0.0f;
    #pragma unroll 4
    for (int it = 0; it < kN / JSPLIT / 64; ++it) {
        int j = jbase + it * 64 + lane;
        float4 cj = c4[j];
        float sqj = cj.x * cj.x + cj.y * cj.y + cj.z * cj.z;
        float k = kraw_f(ci, sqi, cj, sqj);
        if (j != i) s += k;
    }
    #pragma unroll
    for (int off = 32; off; off >>= 1) s += __shfl_xor(s, off, 64);
    if (lane == 0) atomicAdd(&rsum[i], s);
}

// --- kernel 4: fused K write + MFMA GEMM ------------------------------------
// Block: 256 threads = 4 waves; 32 rows x (kN/JSPLIT)-col strip.
// Wave w owns (row-group rg = w>>1, col-half ch = w&1) of each 32x64 window:
// each thread computes exactly its MFMA A-fragment (8 kraw, register-resident
// — r4-proven mapping), stores K via two v4f (r4-proven), and does 8 MFMAs
// with B from double-buffered LDS (r2-proven layout/staging). ONE barrier per
// iteration. Epilogue: r4-proven direct atomicAdd (8 contenders per element).
__global__ __launch_bounds__(256) void main_k(
    const float4* __restrict__ c4, const float* __restrict__ rsum,
    const __bf16* __restrict__ latT, float* __restrict__ outp,
    float* __restrict__ Kout) {

    __shared__ __bf16 Blds[2][kD][LDB];    // 36.9 KB, double-buffered

    const int t = threadIdx.x;
    const int lane = t & 63;
    const int w = t >> 6;
    const int rg = w >> 1;                 // row-group 0/1
    const int ch = w & 1;                  // col-half 0/1
    const int r = lane & 15;               // A-frag row within the 16-row tile
    const int koff = (lane >> 4) * 8;      // A-frag k-chunk within 32-wide step
    const int i0 = blockIdx.x * BMB;
    const int gi = i0 + rg * 16 + r;
    const int jstrip = blockIdx.y * (kN / JSPLIT);
    constexpr int NIT = kN / JSPLIT / BK;  // 32

    const float4 ci = c4[gi];
    const float sqi = ci.x * ci.x + ci.y * ci.y + ci.z * ci.z;
    const float inv_i = 1.0f / (rsum[gi] + 1e-8f);

    v4f acc[8];
    #pragma unroll
    for (int d = 0; d < 8; ++d) acc[d] = (v4f){0.f, 0.f, 0.f, 0.f};

    // prologue: stage window 0 into buffer 0 (r2-proven staging pattern)
    {
        const int j0 = jstrip;
        #pragma unroll
        for (int it = 0; it < 4; ++it) {
            int idx = it * 256 + t;
            int d = idx >> 3, part = idx & 7;
            uint4 v = *reinterpret_cast<const uint4*>(latT + (size_t)d * kN + j0 + part * 8);
            *reinterpret_cast<uint4*>(&Blds[0][d][part * 8]) = v;
        }
    }
    __syncthreads();

    for (int cb = 0; cb < NIT; ++cb) {
        const int p = cb & 1;

        // stage next window into the other buffer (overlaps with compute below)
        if (cb + 1 < NIT) {
            const int j0 = jstrip + (cb + 1) * BK;
            #pragma unroll
            for (int it = 0; it < 4; ++it) {
                int idx = it * 256 + t;
                int d = idx >> 3, part = idx & 7;
                uint4 v = *reinterpret_cast<const uint4*>(latT + (size_t)d * kN + j0 + part * 8);
                *reinterpret_cast<uint4*>(&Blds[p ^ 1][d][part * 8]) = v;
            }
        }

        // this thread's 8 A-fragment elements (rows fixed = gi, cols jc..jc+8)
        const int jc = jstrip + cb * BK + ch * 32 + koff;
        float kn[8];
        #pragma unroll
        for (int e = 0; e < 8; ++e) {
            float4 cj = c4[jc + e];
            float sqj = cj.x * cj.x + cj.y * cj.y + cj.z * cj.z;
            float k = (gi == jc + e) ? 0.0f : kraw_f(ci, sqi, cj, sqj);
            kn[e] = k * inv_i;
        }

        // K output: two 16B stores; lanes {r,r+16,r+32,r+48} tile 128B per row
        float* kp = Kout + (size_t)gi * kN + jc;
        v4f s0 = {kn[0], kn[1], kn[2], kn[3]};
        v4f s1 = {kn[4], kn[5], kn[6], kn[7]};
        *reinterpret_cast<v4f*>(kp)     = s0;
        *reinterpret_cast<v4f*>(kp + 4) = s1;

        v8bf a;
        #pragma unroll
        for (int e = 0; e < 8; ++e) a[e] = (__bf16)kn[e];

        // 8 MFMAs: dims d*16..(d+1)*16, B-frag from LDS (r2-proven mapping)
        #pragma unroll
        for (int d = 0; d < 8; ++d) {
            v8bf b = *reinterpret_cast<const v8bf*>(&Blds[p][d * 16 + r][ch * 32 + koff]);
            acc[d] = __builtin_amdgcn_mfma_f32_16x16x32_bf16(a, b, acc[d], 0, 0, 0);
        }

        __syncthreads();   // staged buffer ready; current buffer free to overwrite
    }

    // epilogue: C/D frag col = lane&15, row = (lane>>4)*4 + q  [m89, r4-proven]
    const int row = (lane >> 4) * 4;
    #pragma unroll
    for (int d = 0; d < 8; ++d)
        #pragma unroll
        for (int q = 0; q < 4; ++q)
            atomicAdd(&outp[(size_t)(i0 + rg * 16 + row + q) * kD + d * 16 + r], acc[d][q]);
}

extern "C" void kernel_launch(void* const* d_in, const int* in_sizes, int n_in,
                              void* d_out, int out_size, void* d_ws, size_t ws_size,
                              hipStream_t stream) {
    const float* latent = (const float*)d_in[0];
    const float* coords = (const float*)d_in[1];
    const float* alpha  = (const float*)d_in[2];

    float* outp = (float*)d_out;                    // [8192][128]
    float* Kout = (float*)d_out + (size_t)kN * kD;  // [8192][8192]

    // ws layout: byte-identical to the proven footprint.
    char* ws = (char*)d_ws;
    __bf16* latT = (__bf16*)ws;                                   // 2 MiB
    float4* c4   = (float4*)(ws + 2u * 1024 * 1024);              // 128 KiB
    float*  rsum = (float*)(ws + 2u * 1024 * 1024 + 128 * 1024);  // 32 KiB

    hipMemsetAsync(outp, 0, (size_t)kN * kD * sizeof(float), stream);
    hipMemsetAsync(rsum, 0, kN * sizeof(float), stream);

    pack_k<<<dim3(kN / 256), dim3(256), 0, stream>>>(coords, alpha, c4);
    transpose_k<<<dim3(kN / 32, kD / 32), dim3(256), 0, stream>>>(latent, latT);
    rowsum_k<<<dim3(kN / 4, JSPLIT), dim3(256), 0, stream>>>(c4, rsum);
    main_k<<<dim3(kN / BMB, JSPLIT), dim3(256), 0, stream>>>(c4, rsum, latT, outp, Kout);
}

// Round 8
// 168.247 us; speedup vs baseline: 1.2378x; 1.2378x over previous
//
#include <hip/hip_runtime.h>
#include <hip/hip_bf16.h>

constexpr int kN = 8192;
constexpr int kD = 128;
constexpr int BM = 16;      // rows per block in main kernel
constexpr int BK = 64;      // j-chunk
constexpr int JSPLIT = 4;   // j-range splits (occupancy)
constexpr int LDB = 72;     // padded LDS row stride (bf16 elems) -> 144B, ~2-way banks

typedef __bf16 v8bf __attribute__((ext_vector_type(8)));
typedef float  v4f  __attribute__((ext_vector_type(4)));

// K_raw with 3 transcendentals (sqrt, log2, exp2) instead of 4:
//   ref: p = clip(D^-a, 1e-8, 1000); K = clip(p * exp(-D/12), 0, 1000)
//   here: t = clamp(-a*0.5*log2(d2), log2(1e-8), log2(1000))
//         K = min(exp2(t - sqrt(d2)*log2(e)/12), 1000)
// Approximation: D = sqrt(d2)+1e-6 -> sqrt(d2); rel err <= 1e-6/D, negligible
// for off-diagonal pairs (diagonal handled separately by callers).
__device__ __forceinline__ float kraw_f(float4 ci, float sqi, float4 cj, float sqj) {
    float d2 = sqi + sqj - 2.0f * (ci.x * cj.x + ci.y * cj.y + ci.z * cj.z);
    d2 = fmaxf(d2, 1e-12f);
    float Dd = __builtin_amdgcn_sqrtf(d2);
    float a = 0.5f * (ci.w + cj.w);
    float t = a * (-0.5f * __builtin_amdgcn_logf(d2));                // -a*log2(D)
    t = fminf(fmaxf(t, -26.575424759098897f), 9.965784284662087f);   // log2(1e-8), log2(1000)
    float K = __builtin_amdgcn_exp2f(fmaf(Dd, -0.12022458674074695f, t));
    return fminf(K, 1000.0f);  // K >= 0 always
}

// --- kernel 1: pack coords+alpha into float4 (proven) ----------------------
__global__ void pack_k(const float* __restrict__ coords, const float* __restrict__ alpha,
                       float4* __restrict__ c4) {
    int j = blockIdx.x * 256 + threadIdx.x;
    if (j < kN) {
        c4[j] = make_float4(coords[3 * j], coords[3 * j + 1], coords[3 * j + 2], alpha[j]);
    }
}

// --- kernel 2: transpose latent [N][128] f32 -> latT [128][N] bf16 (proven) -
__global__ void transpose_k(const float* __restrict__ latent, __bf16* __restrict__ latT) {
    __shared__ float tile[32][33];
    int t = threadIdx.x;
    int tx = t & 31, ty = t >> 5;          // 32 x 8
    int j0 = blockIdx.x * 32, d0 = blockIdx.y * 32;
    #pragma unroll
    for (int i = 0; i < 32; i += 8)
        tile[ty + i][tx] = latent[(size_t)(j0 + ty + i) * kD + d0 + tx];
    __syncthreads();
    #pragma unroll
    for (int i = 0; i < 32; i += 8)
        latT[(size_t)(d0 + ty + i) * kN + j0 + tx] = (__bf16)tile[tx][ty + i];
}

// --- kernel 3: row partial sums -> atomicAdd into rsum (round-6 proven) ----
__global__ __launch_bounds__(256) void rowsum_k(const float4* __restrict__ c4,
                                                float* __restrict__ rsum) {
    int w = threadIdx.x >> 6, lane = threadIdx.x & 63;
    int i = blockIdx.x * 4 + w;
    int jbase = blockIdx.y * (kN / JSPLIT);
    float4 ci = c4[i];
    float sqi = ci.x * ci.x + ci.y * ci.y + ci.z * ci.z;
    float s = 0.0f;
    #pragma unroll 4
    for (int it = 0; it < kN / JSPLIT / 64; ++it) {
        int j = jbase + it * 64 + lane;
        float4 cj = c4[j];
        float sqj = cj.x * cj.x + cj.y * cj.y + cj.z * cj.z;
        float k = kraw_f(ci, sqi, cj, sqj);
        if (j != i) s += k;
    }
    #pragma unroll
    for (int off = 32; off; off >>= 1) s += __shfl_xor(s, off, 64);
    if (lane == 0) atomicAdd(&rsum[i], s);
}

// --- kernel 4: fused K write + MFMA GEMM (round-6 exact structure) ---------
// Block: 256 threads (4 waves), BM=16 rows, j strip of kN/JSPLIT in chunks of
// BK. Wave w computes dims [32w, 32w+32) of the 16x128 output tile; partial
// over its j-strip, atomically accumulated into outp (zeroed by memset).
__global__ __launch_bounds__(256, 2) void main_k(
    const float4* __restrict__ c4, const float* __restrict__ rsum,
    const __bf16* __restrict__ latT, float* __restrict__ outp, float* __restrict__ Kout) {

    __shared__ __bf16 Alds[BM][LDB];    // normalized K tile, bf16
    __shared__ __bf16 Blds[kD][LDB];    // latent^T chunk   [dim][k]
    __shared__ float4 c4row[BM];
    __shared__ float  sqrow[BM];
    __shared__ float  invrow[BM];

    const int t = threadIdx.x;
    const int i0 = blockIdx.x * BM;
    const int jstrip = blockIdx.y * (kN / JSPLIT);

    if (t < BM) {
        float4 ci = c4[i0 + t];
        c4row[t] = ci;
        sqrow[t] = ci.x * ci.x + ci.y * ci.y + ci.z * ci.z;
        invrow[t] = 1.0f / (rsum[i0 + t] + 1e-8f);
    }
    __syncthreads();

    const int lane = t & 63;
    const int wave = t >> 6;
    const int c = t & 63;               // K-tile column owned by this thread
    const int rbase = (t >> 6) * 4;     // 4 K-tile rows owned by this thread

    // MFMA fragment addressing
    const int arow = lane & 15;
    const int koff = (lane >> 4) * 8;
    const int dbase = wave * 32;

    v4f acc0 = {0.f, 0.f, 0.f, 0.f};
    v4f acc1 = {0.f, 0.f, 0.f, 0.f};

    for (int cb = 0; cb < kN / JSPLIT / BK; ++cb) {
        const int j0 = jstrip + cb * BK;

        // stage latT chunk: 128 dims x 64 k, 16B per thread-iter, coalesced
        #pragma unroll
        for (int it = 0; it < 4; ++it) {
            int idx = it * 256 + t;        // 0..1023
            int d = idx >> 3;              // 0..127
            int part = idx & 7;            // 8 x 16B per row
            uint4 v = *reinterpret_cast<const uint4*>(latT + (size_t)d * kN + j0 + part * 8);
            *reinterpret_cast<uint4*>(&Blds[d][part * 8]) = v;
        }

        // compute K tile (16 x 64): thread owns column c, rows rbase..rbase+3
        float4 cj = c4[j0 + c];
        float sqj = cj.x * cj.x + cj.y * cj.y + cj.z * cj.z;
        #pragma unroll
        for (int rr = 0; rr < 4; ++rr) {
            int r = rbase + rr;
            int gi = i0 + r, gj = j0 + c;
            float k = (gi == gj) ? 0.0f : kraw_f(c4row[r], sqrow[r], cj, sqj);
            float kn = k * invrow[r];
            Kout[(size_t)gi * kN + gj] = kn;          // coalesced 256B per row per wave
            Alds[r][c] = (__bf16)kn;
        }
        __syncthreads();

        // MFMA: A = K tile (16x64), B = latT chunk (64 x 32 dims for this wave)
        #pragma unroll
        for (int kk = 0; kk < 2; ++kk) {
            v8bf a  = *reinterpret_cast<const v8bf*>(&Alds[arow][kk * 32 + koff]);
            v8bf b0 = *reinterpret_cast<const v8bf*>(&Blds[dbase + (lane & 15)][kk * 32 + koff]);
            v8bf b1 = *reinterpret_cast<const v8bf*>(&Blds[dbase + 16 + (lane & 15)][kk * 32 + koff]);
            acc0 = __builtin_amdgcn_mfma_f32_16x16x32_bf16(a, b0, acc0, 0, 0, 0);
            acc1 = __builtin_amdgcn_mfma_f32_16x16x32_bf16(a, b1, acc1, 0, 0, 0);
        }
        __syncthreads();
    }

    // epilogue: D frag layout col = lane&15, row = (lane>>4)*4 + q  [m89]
    const int row = (lane >> 4) * 4;
    const int col0 = wave * 32 + (lane & 15);
    #pragma unroll
    for (int q = 0; q < 4; ++q) {
        atomicAdd(&outp[(size_t)(i0 + row + q) * kD + col0],      acc0[q]);
        atomicAdd(&outp[(size_t)(i0 + row + q) * kD + col0 + 16], acc1[q]);
    }
}

extern "C" void kernel_launch(void* const* d_in, const int* in_sizes, int n_in,
                              void* d_out, int out_size, void* d_ws, size_t ws_size,
                              hipStream_t stream) {
    const float* latent = (const float*)d_in[0];
    const float* coords = (const float*)d_in[1];
    const float* alpha  = (const float*)d_in[2];

    float* outp = (float*)d_out;                    // [8192][128]
    float* Kout = (float*)d_out + (size_t)kN * kD;  // [8192][8192]

    // ws layout: byte-identical to the proven footprint.
    char* ws = (char*)d_ws;
    __bf16* latT = (__bf16*)ws;                                   // 2 MiB
    float4* c4   = (float4*)(ws + 2u * 1024 * 1024);              // 128 KiB
    float*  rsum = (float*)(ws + 2u * 1024 * 1024 + 128 * 1024);  // 32 KiB

    hipMemsetAsync(outp, 0, (size_t)kN * kD * sizeof(float), stream);
    hipMemsetAsync(rsum, 0, kN * sizeof(float), stream);

    pack_k<<<dim3(kN / 256), dim3(256), 0, stream>>>(coords, alpha, c4);
    transpose_k<<<dim3(kN / 32, kD / 32), dim3(256), 0, stream>>>(latent, latT);
    rowsum_k<<<dim3(kN / 4, JSPLIT), dim3(256), 0, stream>>>(c4, rsum);
    main_k<<<dim3(kN / BM, JSPLIT), dim3(256), 0, stream>>>(c4, rsum, latT, outp, Kout);
}